// Round 11
// baseline (195.717 us; speedup 1.0000x reference)
//
#include <hip/hip_runtime.h>
#include <hip/hip_bf16.h>
#include <math.h>

typedef __attribute__((ext_vector_type(8))) short bf16x8;
typedef __attribute__((ext_vector_type(4))) short s16x4;
typedef __attribute__((ext_vector_type(4))) float f32x4;

constexpr int cB = 2, cS = 2048, cH = 16, cD = 64, cIn = 1024, cM = 1024;
constexpr float cLog2e = 1.4426950408889634f;

union BfPack { bf16x8 v; short s[8]; };
union BfPack4 { s16x4 v; short s[4]; };

__device__ __forceinline__ short f2bf(float f) {
    union { float f; unsigned u; } v; v.f = f;
    unsigned r = v.u + 0x7fffu + ((v.u >> 16) & 1u);   // round-to-nearest-even
    return (short)(r >> 16);
}

__device__ __forceinline__ f32x4 mfma16(bf16x8 a, bf16x8 b, f32x4 c) {
    return __builtin_amdgcn_mfma_f32_16x16x32_bf16(a, b, c, 0, 0, 0);
}

__device__ __forceinline__ void async16(const short* g, short* l) {
    __builtin_amdgcn_global_load_lds(
        (const __attribute__((address_space(1))) unsigned*)(uintptr_t)g,
        (__attribute__((address_space(3))) unsigned*)(uintptr_t)l, 16, 0, 0);
}

// ---------------------------------------------------------------------------
// Kernel 1 (merged prep): blocks [0,2048) hidden fp32->bf16;
// [2048,3072) weight transpose+convert; [3072,3088) bias table + mask.
// ---------------------------------------------------------------------------
__global__ __launch_bounds__(256) void prep_kernel(
    const float* __restrict__ hidden, short* __restrict__ hbf,
    const float* __restrict__ Wq, const float* __restrict__ Wk,
    const float* __restrict__ Wv, const float* __restrict__ Wo,
    short* __restrict__ Wt,
    const float* __restrict__ rel_bias, const int* __restrict__ mask,
    float* __restrict__ bt, float* __restrict__ maskadd) {
    const int bid = blockIdx.x;
    const int tid = threadIdx.x;
    if (bid < 2048) {
        // ---- hidden fp32 -> bf16, flat
        int t = bid * 256 + tid;
        const float4* src = (const float4*)hidden;
        float4 a = src[2 * t], b = src[2 * t + 1];
        BfPack p;
        p.s[0] = f2bf(a.x); p.s[1] = f2bf(a.y); p.s[2] = f2bf(a.z); p.s[3] = f2bf(a.w);
        p.s[4] = f2bf(b.x); p.s[5] = f2bf(b.y); p.s[6] = f2bf(b.z); p.s[7] = f2bf(b.w);
        ((bf16x8*)hbf)[t] = p.v;
    } else if (bid < 3072) {
        // ---- weights fp32 [K][N] -> bf16 transposed Wt[z][N][K]
        const int b2 = bid - 2048;
        const int z = b2 >> 8, rem = b2 & 255;
        const float* W = (z == 0) ? Wq : (z == 1) ? Wk : (z == 2) ? Wv : Wo;
        const float scale = (z == 0) ? 0.125f * cLog2e : 1.0f;
        const int n0 = (rem & 15) * 64, k0 = (rem >> 4) * 64;
        __shared__ short sW[64][72];     // [k][n]
        const int r = tid >> 2, c4 = (tid & 3) * 16;
        {
            const float* src = W + (size_t)(k0 + r) * cM + n0 + c4;
            BfPack p[2];
            #pragma unroll
            for (int q = 0; q < 2; q++) {
                float4 x = ((const float4*)src)[2 * q];
                float4 y = ((const float4*)src)[2 * q + 1];
                p[q].s[0] = f2bf(x.x * scale); p[q].s[1] = f2bf(x.y * scale);
                p[q].s[2] = f2bf(x.z * scale); p[q].s[3] = f2bf(x.w * scale);
                p[q].s[4] = f2bf(y.x * scale); p[q].s[5] = f2bf(y.y * scale);
                p[q].s[6] = f2bf(y.z * scale); p[q].s[7] = f2bf(y.w * scale);
            }
            *(bf16x8*)&sW[r][c4] = p[0].v;
            *(bf16x8*)&sW[r][c4 + 8] = p[1].v;
        }
        __syncthreads();
        const int n = tid >> 2, kc = (tid & 3) * 16;
        BfPack o0, o1;
        #pragma unroll
        for (int j = 0; j < 8; j++) o0.s[j] = sW[kc + j][n];
        #pragma unroll
        for (int j = 0; j < 8; j++) o1.s[j] = sW[kc + 8 + j][n];
        short* dst = Wt + (size_t)z * cM * cIn + (size_t)(n0 + n) * cIn + k0 + kc;
        *(bf16x8*)dst = o0.v;
        *(bf16x8*)(dst + 8) = o1.v;
    } else {
        // ---- bias table (pre-scaled log2e) + mask add
        int idx = (bid - 3072) * 256 + tid;
        if (idx < 4096) maskadd[idx] = (1.0f - (float)mask[idx]) * -3.0e38f;
        if (idx >= 4095) return;
        int delta = idx - 2047;
        int rb = (delta > 0) ? 16 : 0;
        int ar = delta < 0 ? -delta : delta;
        int bucket;
        if (ar < 8) {
            bucket = rb + ar;
        } else {
            float rl = 8.0f + logf((float)ar * 0.125f) * 2.8853900817779268f;
            rl = fminf(rl, 15.0f);
            bucket = rb + (int)rl;
        }
        #pragma unroll
        for (int h = 0; h < cH; h++)
            bt[h * 4096 + 2048 + delta] = rel_bias[bucket * cH + h] * cLog2e;
    }
}

// ---------------------------------------------------------------------------
// Kernel 3: QKV GEMM, 64x128 tiles (gemm_o's proven retile applied):
// 1536 blocks = 6 blocks/CU = 24 waves/CU (was 128x128, 768 blocks, 3/CU,
// latency-starved). 2-phase double-buffered staging (24 KB LDS).
// z=0 Q row-major (log2e-scaled), z=1 K row-major, z=2 V^T kappa layout.
// Epilogues via LDS transpose -> coalesced 16B stores.
// ---------------------------------------------------------------------------
__global__ __launch_bounds__(256) void gemm_qkv_kernel(
    const short* __restrict__ hbf, const short* __restrict__ Wt,
    short* __restrict__ Qrm, short* __restrict__ Krm, short* __restrict__ VT) {
    const int bid = blockIdx.x;              // [0,1536)
    const int z = bid >> 9;
    const int rem = bid & 511;
    const int m0 = (rem & 63) * 64;
    const int c0 = (rem >> 6) * 128;
    const short* Bt = Wt + (size_t)z * cM * cIn;

    __shared__ short smem[12288];            // 2 bufs x (sA 2048 + sB 4096)
    const int tid = threadIdx.x, w = tid >> 6, l = tid & 63;
    const int m16 = l & 15, g = l >> 4;
    const int wm = (w & 1) * 32, wn = (w >> 1) * 64;
    const int sr = tid >> 2, sc = (tid & 3) * 8;
    f32x4 acc[2][4] = {};

    const short* pA = hbf + (size_t)(m0 + sr) * cIn + sc;
    const short* pB0 = Bt + (size_t)(c0 + sr) * cIn + sc;
    const short* pB1 = Bt + (size_t)(c0 + 64 + sr) * cIn + sc;

    // prologue: k0 = 0 -> buf 0
    async16(pA, smem + tid * 8);
    async16(pB0, smem + 2048 + tid * 8);
    async16(pB1, smem + 4096 + tid * 8);
    __syncthreads();

    for (int k0 = 0; k0 < cIn; k0 += 32) {
        const int buf = (k0 >> 5) & 1;
        if (k0 + 32 < cIn) {           // stage next K-step
            short* dn = smem + (buf ^ 1) * 6144 + tid * 8;
            async16(pA + k0 + 32, dn);
            async16(pB0 + k0 + 32, dn + 2048);
            async16(pB1 + k0 + 32, dn + 4096);
        }
        const short* sA = smem + buf * 6144;
        const short* sB = sA + 2048;
        bf16x8 af[2], bf[4];
        #pragma unroll
        for (int i = 0; i < 2; i++)
            af[i] = *(const bf16x8*)(sA + (wm + i * 16 + m16) * 32 + g * 8);
        #pragma unroll
        for (int jj = 0; jj < 4; jj++)
            bf[jj] = *(const bf16x8*)(sB + (wn + jj * 16 + m16) * 32 + g * 8);
        #pragma unroll
        for (int i = 0; i < 2; i++)
            #pragma unroll
            for (int jj = 0; jj < 4; jj++)
                acc[i][jj] = (z == 2) ? mfma16(bf[jj], af[i], acc[i][jj])
                                      : mfma16(af[i], bf[jj], acc[i][jj]);
        __syncthreads();   // staging (buf^1) landed + all reads of buf done
    }

    if (z <= 1) {
        // D[m][n]: m = wm+i*16+g*4+r, n = wn+jj*16+m16.  Tile [64][132].
        #pragma unroll
        for (int i = 0; i < 2; i++)
            #pragma unroll
            for (int jj = 0; jj < 4; jj++)
                #pragma unroll
                for (int r = 0; r < 4; r++)
                    smem[(wm + i * 16 + g * 4 + r) * 132 + wn + jj * 16 + m16] =
                        f2bf(acc[i][jj][r]);
        __syncthreads();
        const int tr = tid >> 2, hf = (tid & 3) * 32;
        short* dst = ((z == 0) ? Qrm : Krm) + (size_t)(m0 + tr) * cM + c0 + hf;
        #pragma unroll
        for (int c = 0; c < 4; c++)
            *(bf16x8*)(dst + c * 8) = *(const bf16x8*)(smem + tr * 132 + hf + c * 8);
    } else {
        // SWAP: D[n][m]: n = wn+jj*16+g*4+r (wcol side), m = wm+i*16+m16 (ss).
        // Scatter to [128 wcol][68 kappa(ss)].
        #pragma unroll
        for (int i = 0; i < 2; i++) {
            const int sl = wm + i * 16 + m16;          // ss local, [0,64)
            const int pcol = (sl & 3) | ((sl & 28) << 1) | ((sl >> 3) & 4);
            #pragma unroll
            for (int jj = 0; jj < 4; jj++)
                #pragma unroll
                for (int r = 0; r < 4; r++)
                    smem[(wn + jj * 16 + g * 4 + r) * 68 + pcol] =
                        f2bf(acc[i][jj][r]);
        }
        __syncthreads();
        const int tr = tid >> 1, hf = (tid & 1) * 32;
        const int wcol = c0 + tr;                      // h*64 + d
        short* dst = VT + (((size_t)(m0 >> 11) * cH + (wcol >> 6)) * cD +
                           (wcol & 63)) * cS + (m0 & 2047) + hf;
        #pragma unroll
        for (int c = 0; c < 4; c++)
            *(bf16x8*)(dst + c * 8) = *(const bf16x8*)(smem + tr * 68 + hf + c * 8);
    }
}

// ---------------------------------------------------------------------------
// Kernel 4: flash attention (8-wave blocks, qq=2, KVBLK=128, XCD-pinned,
// K+V dbuf LDS, LDS bias window).  R11 deltas:
//  - bias+mask folded into the MFMA acc-init (saves 64 v_adds/wave-tile;
//    safe now that bias comes from LDS, unlike the R4-era global gather)
//  - mask row staged into LDS once (drops 8 global dwordx4 + addressing
//    per tile)
// ---------------------------------------------------------------------------
__global__ __launch_bounds__(512, 1) void attn_kernel(
    const short* __restrict__ Qrm, const short* __restrict__ Krm,
    const short* __restrict__ VTK, const float* __restrict__ maskadd,
    const float* __restrict__ bias_t, short* __restrict__ ctx) {
    // raw -> (xcd, q-block, bh-group): all 8 q-blocks of a (b,h) on one XCD
    const int raw = blockIdx.x;              // [0,256)
    const int xcd = raw & 7, j = raw >> 3;
    const int qi = j & 7, grp = j >> 3;      // grp in [0,4)
    const int bh = grp * 8 + xcd;            // [0,32)
    const int b = bh >> 4, h = bh & 15;
    const int q0 = qi * 256;

    const short* VTp = VTK + ((size_t)b * cH + h) * cS * cD;   // [d][kappa]
    const float* mp = maskadd + b * cS;

    const int tid = threadIdx.x;             // [0,512)
    const int wave = tid >> 6, lane = tid & 63;
    const int m16 = lane & 15, g = lane >> 4;

    __shared__ short Kt[2][128 * 64];    // [buf][key][d-unit swz]   32 KB
    __shared__ short Vt[2][64 * 128];    // [buf][d][kappa-unit swz] 32 KB
    __shared__ float bias_lds[2304];     // delta window, 9.2 KB
    __shared__ float mask_lds[2048];     // this batch's mask row, 8 KB

    // ---- stage bias window + mask row once
    {
        const float* bw = bias_t + h * 4096 + 2048 - (q0 + 255);
        for (int i = tid; i < 2303; i += 512)
            bias_lds[i] = bw[i];
        ((f32x4*)mask_lds)[tid & 511] = ((const f32x4*)mp)[tid & 511];
    }

    int qv[2];
    bf16x8 qf[2][2];
    #pragma unroll
    for (int qq = 0; qq < 2; qq++) {
        qv[qq] = q0 + wave * 16 + qq * 128 + m16;
        const short* qb = Qrm + (size_t)(b * cS + qv[qq]) * cM + h * cD;
        qf[qq][0] = *(const bf16x8*)(qb + g * 8);
        qf[qq][1] = *(const bf16x8*)(qb + 32 + g * 8);
    }

    // per-lane base index into bias_lds: idx = ib[qq] + kt + st*16 + c
    int ib[2];
    #pragma unroll
    for (int qq = 0; qq < 2; qq++)
        ib[qq] = q0 + 255 + g * 4 - qv[qq];

    f32x4 o[2][4] = {};
    f32x4 lacc[2] = {};
    BfPack ones;
    #pragma unroll
    for (int i = 0; i < 8; i++) ones.s[i] = (short)0x3F80;   // bf16 1.0

    // staging: 512 threads -> 2 async16 per array per tile
    const int u8 = tid & 7, r8 = tid >> 3;      // r8 in [0,64)
    const int u16s = tid & 15, r16 = tid >> 4;  // r16 in [0,32)
    const short* pK = Krm + ((size_t)b * cS + r8) * cM + h * cD +
                      ((u8 ^ (r8 & 7)) << 3);
    const short* pV = VTp + (size_t)r16 * cS + ((u16s ^ (r16 & 7)) << 3);
    short* dK = (short*)Kt + tid * 8;
    short* dV = (short*)Vt + tid * 8;

    const int kx0 = ((g ^ (m16 & 7)) << 3);          // lo 16B unit
    const int kx1 = (((g + 4) ^ (m16 & 7)) << 3);    // hi 16B unit

    #pragma unroll
    for (int c = 0; c < 2; c++) {
        async16(pK + (size_t)(c * 64) * cM, dK + c * 4096);
        async16(pV + (size_t)(c * 32) * cS, dV + c * 4096);
    }
    __syncthreads();        // bias/mask staged + tile 0 landed

    for (int kt = 0; kt < cS; kt += 128) {
        const int buf = (kt >> 7) & 1, nxt = buf ^ 1;
        if (kt + 128 < cS) {           // stage next tile (uniform branch)
            #pragma unroll
            for (int c = 0; c < 2; c++) {
                async16(pK + (size_t)(kt + 128 + c * 64) * cM,
                        dK + nxt * 8192 + c * 4096);
                async16(pV + (size_t)(c * 32) * cS + kt + 128,
                        dV + nxt * 8192 + c * 4096);
            }
        }
        const short* K_ = (const short*)Kt + buf * 8192;
        const short* V_ = (const short*)Vt + buf * 8192;
        const int iq0 = ib[0] + kt, iq1 = ib[1] + kt;   // 2 adds per tile

        #pragma unroll
        for (int h2 = 0; h2 < 2; h2++) {
            // ---- bias + mask from LDS (compile-time DS offsets)
            f32x4 binit[2][4];
            #pragma unroll
            for (int t4 = 0; t4 < 4; t4++) {
                const int sto = (h2 * 4 + t4) * 16;
                f32x4 mk = *(const f32x4*)(mask_lds + kt + sto + g * 4);
                #pragma unroll
                for (int c = 0; c < 4; c++) {
                    binit[0][t4][c] = bias_lds[iq0 + sto + c] + mk[c];
                    binit[1][t4][c] = bias_lds[iq1 + sto + c] + mk[c];
                }
            }

            // ---- S^T with bias+mask pre-loaded into the accumulator
            f32x4 s[2][4];
            __builtin_amdgcn_s_setprio(1);
            #pragma unroll
            for (int t4 = 0; t4 < 4; t4++) {
                const int st = h2 * 4 + t4;
                bf16x8 klo = *(const bf16x8*)(K_ + (st * 16 + m16) * 64 + kx0);
                bf16x8 khi = *(const bf16x8*)(K_ + (st * 16 + m16) * 64 + kx1);
                #pragma unroll
                for (int qq = 0; qq < 2; qq++)
                    s[qq][t4] = mfma16(khi, qf[qq][1],
                                       mfma16(klo, qf[qq][0], binit[qq][t4]));
            }
            __builtin_amdgcn_s_setprio(0);

            // ---- softmax numerator: exp2(s), pack P frags
            BfPack pp[2][2];
            #pragma unroll
            for (int qq = 0; qq < 2; qq++)
                #pragma unroll
                for (int t4 = 0; t4 < 4; t4++)
                    #pragma unroll
                    for (int r = 0; r < 2; r++) {
                        float p0 = __builtin_amdgcn_exp2f(s[qq][t4][2 * r]);
                        float p1 = __builtin_amdgcn_exp2f(s[qq][t4][2 * r + 1]);
                        __hip_bfloat162 h2v = __float22bfloat162_rn(float2{p0, p1});
                        short2 sp = *(short2*)&h2v;
                        pp[qq][t4 & 1].s[(t4 >> 1) * 4 + 2 * r]     = sp.x;
                        pp[qq][t4 & 1].s[(t4 >> 1) * 4 + 2 * r + 1] = sp.y;
                    }

            // ---- denominator on the matrix pipe + O^T = V^T @ P
            __builtin_amdgcn_s_setprio(1);
            #pragma unroll
            for (int qq = 0; qq < 2; qq++) {
                lacc[qq] = mfma16(ones.v, pp[qq][0].v, lacc[qq]);
                lacc[qq] = mfma16(ones.v, pp[qq][1].v, lacc[qq]);
            }
            #pragma unroll
            for (int nt = 0; nt < 4; nt++) {
                bf16x8 vlo = *(const bf16x8*)(V_ + (nt * 16 + m16) * 128 +
                                              h2 * 64 + kx0);
                bf16x8 vhi = *(const bf16x8*)(V_ + (nt * 16 + m16) * 128 +
                                              h2 * 64 + kx1);
                #pragma unroll
                for (int qq = 0; qq < 2; qq++) {
                    o[qq][nt] = mfma16(vlo, pp[qq][0].v, o[qq][nt]);
                    o[qq][nt] = mfma16(vhi, pp[qq][1].v, o[qq][nt]);
                }
            }
            __builtin_amdgcn_s_setprio(0);
        }

        __syncthreads();   // staging (nxt) complete + all reads of buf done
    }

    #pragma unroll
    for (int qq = 0; qq < 2; qq++) {
        const float inv = 1.0f / lacc[qq][0];   // all 4 regs identical
        short* cb = ctx + (size_t)(b * cS + qv[qq]) * cM + h * cD;
        #pragma unroll
        for (int nt = 0; nt < 4; nt++) {
            BfPack4 pk;
            #pragma unroll
            for (int r = 0; r < 4; r++) pk.s[r] = f2bf(o[qq][nt][r] * inv);
            *(s16x4*)(cb + nt * 16 + g * 4) = pk.v;
        }
    }
}

// ---------------------------------------------------------------------------
// Kernel 5: out fp32 = ctx(bf16) @ WoT.  64x128 tile, 512 blocks,
// 2-phase double-buffered staging (R9/R10-proven, unchanged).
// ---------------------------------------------------------------------------
__global__ __launch_bounds__(256) void gemm_o_kernel(
    const short* __restrict__ ctx, const short* __restrict__ WoT,
    float* __restrict__ out) {
    const int raw = blockIdx.x;              // [0,512)
    const int xcd = raw & 7;
    const int rest = raw >> 3;               // [0,64)
    const int cblk = rest & 7;
    const int m0 = (xcd * 8 + (rest >> 3)) * 64;
    const int c0 = cblk * 128;

    __shared__ short smem[12288];        // 2 bufs x (sA 2048 + sB 4096)
    const int tid = threadIdx.x, w = tid >> 6, l = tid & 63;
    const int m16 = l & 15, g = l >> 4;
    const int wm = (w & 1) * 32, wn = (w >> 1) * 64;
    const int sr = tid >> 2, sc = (tid & 3) * 8;
    f32x4 acc[2][4] = {};

    const short* pA = ctx + (size_t)(m0 + sr) * cIn + sc;
    const short* pB0 = WoT + (size_t)(c0 + sr) * cIn + sc;
    const short* pB1 = WoT + (size_t)(c0 + 64 + sr) * cIn + sc;

    // prologue: k0 = 0 -> buf 0
    async16(pA, smem + tid * 8);
    async16(pB0, smem + 2048 + tid * 8);
    async16(pB1, smem + 4096 + tid * 8);
    __syncthreads();

    for (int k0 = 0; k0 < cIn; k0 += 32) {
        const int buf = (k0 >> 5) & 1;
        if (k0 + 32 < cIn) {           // stage next K-step
            short* dn = smem + (buf ^ 1) * 6144 + tid * 8;
            async16(pA + k0 + 32, dn);
            async16(pB0 + k0 + 32, dn + 2048);
            async16(pB1 + k0 + 32, dn + 4096);
        }
        const short* sA = smem + buf * 6144;
        const short* sB = sA + 2048;
        bf16x8 af[2], bf[4];
        #pragma unroll
        for (int i = 0; i < 2; i++)
            af[i] = *(const bf16x8*)(sA + (wm + i * 16 + m16) * 32 + g * 8);
        #pragma unroll
        for (int jj = 0; jj < 4; jj++)
            bf[jj] = *(const bf16x8*)(sB + (wn + jj * 16 + m16) * 32 + g * 8);
        #pragma unroll
        for (int i = 0; i < 2; i++)
            #pragma unroll
            for (int jj = 0; jj < 4; jj++)
                acc[i][jj] = mfma16(af[i], bf[jj], acc[i][jj]);
        __syncthreads();   // staging (buf^1) landed + all reads of buf done
    }
    #pragma unroll
    for (int i = 0; i < 2; i++)
        #pragma unroll
        for (int jj = 0; jj < 4; jj++)
            #pragma unroll
            for (int r = 0; r < 4; r++)
                out[(size_t)(m0 + wm + i * 16 + g * 4 + r) * cM +
                    c0 + wn + jj * 16 + m16] = acc[i][jj][r];
}

extern "C" void kernel_launch(void* const* d_in, const int* in_sizes, int n_in,
                              void* d_out, int out_size, void* d_ws, size_t ws_size,
                              hipStream_t stream) {
    const float* hidden   = (const float*)d_in[0];
    const int*   mask     = (const int*)d_in[1];
    const float* Wq       = (const float*)d_in[2];
    const float* Wk       = (const float*)d_in[3];
    const float* Wv       = (const float*)d_in[4];
    const float* Wo       = (const float*)d_in[5];
    const float* rel_bias = (const float*)d_in[6];
    float* out = (float*)d_out;

    // ws (shorts): hbf/ctx 4M | Wt 4x1M | Q 4M | K 4M | VT 4M | bias 256KB | mask 16KB
    short* hbf_ctx = (short*)d_ws;
    short* Wt  = hbf_ctx + (size_t)4 * 1024 * 1024;
    short* Qrm = Wt  + (size_t)4 * 1024 * 1024;
    short* Krm = Qrm + (size_t)4 * 1024 * 1024;
    short* VT  = Krm + (size_t)4 * 1024 * 1024;
    float* bias_t  = (float*)(VT + (size_t)4 * 1024 * 1024);
    float* maskf   = bias_t + 16 * 4096;

    prep_kernel<<<3088, 256, 0, stream>>>(hidden, hbf_ctx, Wq, Wk, Wv, Wo, Wt,
                                          rel_bias, mask, bias_t, maskf);
    gemm_qkv_kernel<<<1536, 256, 0, stream>>>(hbf_ctx, Wt, Qrm, Krm, VT);
    attn_kernel<<<256, 512, 0, stream>>>(Qrm, Krm, VT, maskf, bias_t, hbf_ctx);
    gemm_o_kernel<<<512, 256, 0, stream>>>(hbf_ctx, Wt + (size_t)3 * 1024 * 1024,
                                           out);
}

// Round 12
// 187.174 us; speedup vs baseline: 1.0456x; 1.0456x over previous
//
#include <hip/hip_runtime.h>
#include <hip/hip_bf16.h>
#include <math.h>

typedef __attribute__((ext_vector_type(8))) short bf16x8;
typedef __attribute__((ext_vector_type(4))) short s16x4;
typedef __attribute__((ext_vector_type(4))) float f32x4;

constexpr int cB = 2, cS = 2048, cH = 16, cD = 64, cIn = 1024, cM = 1024;
constexpr float cLog2e = 1.4426950408889634f;

union BfPack { bf16x8 v; short s[8]; };
union BfPack4 { s16x4 v; short s[4]; };

__device__ __forceinline__ short f2bf(float f) {
    union { float f; unsigned u; } v; v.f = f;
    unsigned r = v.u + 0x7fffu + ((v.u >> 16) & 1u);   // round-to-nearest-even
    return (short)(r >> 16);
}

__device__ __forceinline__ f32x4 mfma16(bf16x8 a, bf16x8 b, f32x4 c) {
    return __builtin_amdgcn_mfma_f32_16x16x32_bf16(a, b, c, 0, 0, 0);
}

__device__ __forceinline__ void async16(const short* g, short* l) {
    __builtin_amdgcn_global_load_lds(
        (const __attribute__((address_space(1))) unsigned*)(uintptr_t)g,
        (__attribute__((address_space(3))) unsigned*)(uintptr_t)l, 16, 0, 0);
}

// ---------------------------------------------------------------------------
// Kernel 1 (merged prep): blocks [0,2048) hidden fp32->bf16;
// [2048,3072) weight transpose+convert; [3072,3088) bias table + mask.
// ---------------------------------------------------------------------------
__global__ __launch_bounds__(256) void prep_kernel(
    const float* __restrict__ hidden, short* __restrict__ hbf,
    const float* __restrict__ Wq, const float* __restrict__ Wk,
    const float* __restrict__ Wv, const float* __restrict__ Wo,
    short* __restrict__ Wt,
    const float* __restrict__ rel_bias, const int* __restrict__ mask,
    float* __restrict__ bt, float* __restrict__ maskadd) {
    const int bid = blockIdx.x;
    const int tid = threadIdx.x;
    if (bid < 2048) {
        // ---- hidden fp32 -> bf16, flat
        int t = bid * 256 + tid;
        const float4* src = (const float4*)hidden;
        float4 a = src[2 * t], b = src[2 * t + 1];
        BfPack p;
        p.s[0] = f2bf(a.x); p.s[1] = f2bf(a.y); p.s[2] = f2bf(a.z); p.s[3] = f2bf(a.w);
        p.s[4] = f2bf(b.x); p.s[5] = f2bf(b.y); p.s[6] = f2bf(b.z); p.s[7] = f2bf(b.w);
        ((bf16x8*)hbf)[t] = p.v;
    } else if (bid < 3072) {
        // ---- weights fp32 [K][N] -> bf16 transposed Wt[z][N][K]
        const int b2 = bid - 2048;
        const int z = b2 >> 8, rem = b2 & 255;
        const float* W = (z == 0) ? Wq : (z == 1) ? Wk : (z == 2) ? Wv : Wo;
        const float scale = (z == 0) ? 0.125f * cLog2e : 1.0f;
        const int n0 = (rem & 15) * 64, k0 = (rem >> 4) * 64;
        __shared__ short sW[64][72];     // [k][n]
        const int r = tid >> 2, c4 = (tid & 3) * 16;
        {
            const float* src = W + (size_t)(k0 + r) * cM + n0 + c4;
            BfPack p[2];
            #pragma unroll
            for (int q = 0; q < 2; q++) {
                float4 x = ((const float4*)src)[2 * q];
                float4 y = ((const float4*)src)[2 * q + 1];
                p[q].s[0] = f2bf(x.x * scale); p[q].s[1] = f2bf(x.y * scale);
                p[q].s[2] = f2bf(x.z * scale); p[q].s[3] = f2bf(x.w * scale);
                p[q].s[4] = f2bf(y.x * scale); p[q].s[5] = f2bf(y.y * scale);
                p[q].s[6] = f2bf(y.z * scale); p[q].s[7] = f2bf(y.w * scale);
            }
            *(bf16x8*)&sW[r][c4] = p[0].v;
            *(bf16x8*)&sW[r][c4 + 8] = p[1].v;
        }
        __syncthreads();
        const int n = tid >> 2, kc = (tid & 3) * 16;
        BfPack o0, o1;
        #pragma unroll
        for (int j = 0; j < 8; j++) o0.s[j] = sW[kc + j][n];
        #pragma unroll
        for (int j = 0; j < 8; j++) o1.s[j] = sW[kc + 8 + j][n];
        short* dst = Wt + (size_t)z * cM * cIn + (size_t)(n0 + n) * cIn + k0 + kc;
        *(bf16x8*)dst = o0.v;
        *(bf16x8*)(dst + 8) = o1.v;
    } else {
        // ---- bias table (pre-scaled log2e) + mask add
        int idx = (bid - 3072) * 256 + tid;
        if (idx < 4096) maskadd[idx] = (1.0f - (float)mask[idx]) * -3.0e38f;
        if (idx >= 4095) return;
        int delta = idx - 2047;
        int rb = (delta > 0) ? 16 : 0;
        int ar = delta < 0 ? -delta : delta;
        int bucket;
        if (ar < 8) {
            bucket = rb + ar;
        } else {
            float rl = 8.0f + logf((float)ar * 0.125f) * 2.8853900817779268f;
            rl = fminf(rl, 15.0f);
            bucket = rb + (int)rl;
        }
        #pragma unroll
        for (int h = 0; h < cH; h++)
            bt[h * 4096 + 2048 + delta] = rel_bias[bucket * cH + h] * cLog2e;
    }
}

// ---------------------------------------------------------------------------
// GEMM core, 128x128 tile, 2-PHASE double-buffered (R10-proven best):
// stage tile t+1 into buf^1 BEFORE computing tile t; one barrier per K-step.
// LDS: 2 x 8192 shorts = 32 KB (fits in caller's 128x132 epilogue buffer).
// ---------------------------------------------------------------------------
template <bool SWAP>
__device__ __forceinline__ void gemm_core(
    const short* __restrict__ A, const short* __restrict__ Bt,
    short* smem, int m0, int c0, int tid, f32x4 (&acc)[4][4]) {
    const int w = tid >> 6, l = tid & 63;
    const int m16 = l & 15, g = l >> 4;
    const int srow = l >> 2, scol = (l & 3) * 8;
    const int mq = (w & 1) * 64, nq = (w >> 1) * 64;

    const short* pA0 = A + (size_t)(m0 + w * 16 + srow) * cIn + scol;
    const short* pA1 = A + (size_t)(m0 + 64 + w * 16 + srow) * cIn + scol;
    const short* pB0 = Bt + (size_t)(c0 + w * 16 + srow) * cIn + scol;
    const short* pB1 = Bt + (size_t)(c0 + 64 + w * 16 + srow) * cIn + scol;
    const int dof = w * 512 + l * 8;

    // prologue: k0 = 0 -> buf 0
    async16(pA0, smem + dof);
    async16(pA1, smem + 2048 + dof);
    async16(pB0, smem + 4096 + dof);
    async16(pB1, smem + 6144 + dof);
    __syncthreads();

    for (int k0 = 0; k0 < cIn; k0 += 32) {
        const int buf = (k0 >> 5) & 1;
        if (k0 + 32 < cIn) {           // stage next K-step (uniform branch)
            short* dn = smem + (buf ^ 1) * 8192 + dof;
            async16(pA0 + k0 + 32, dn);
            async16(pA1 + k0 + 32, dn + 2048);
            async16(pB0 + k0 + 32, dn + 4096);
            async16(pB1 + k0 + 32, dn + 6144);
        }
        const short* sA = smem + buf * 8192;
        const short* sB = sA + 4096;
        bf16x8 af[4], bf[4];
        #pragma unroll
        for (int i = 0; i < 4; i++)
            af[i] = *(const bf16x8*)(sA + (mq + i * 16 + m16) * 32 + g * 8);
        #pragma unroll
        for (int j = 0; j < 4; j++)
            bf[j] = *(const bf16x8*)(sB + (nq + j * 16 + m16) * 32 + g * 8);
        #pragma unroll
        for (int i = 0; i < 4; i++)
            #pragma unroll
            for (int j = 0; j < 4; j++)
                acc[i][j] = SWAP ? mfma16(bf[j], af[i], acc[i][j])
                                 : mfma16(af[i], bf[j], acc[i][j]);
        __syncthreads();   // staging (buf^1) landed + all reads of buf done
    }
}

// ---------------------------------------------------------------------------
// Kernel 3: QKV GEMM — R10 config (128x128 tile, 768 blocks, XCD-pinned
// 1-D grid: all 24 blocks sharing an A-row-panel land on one XCD).
// R11's 64x128 retile regressed (staging-ops/MFMA 0.25->0.375); reverted.
// z=0 Q row-major (log2e-scaled), z=1 K row-major, z=2 V^T kappa layout.
// Epilogues via LDS transpose tile (128x132 pad) -> coalesced 16B stores.
// ---------------------------------------------------------------------------
__global__ __launch_bounds__(256) void gemm_qkv_kernel(
    const short* __restrict__ hbf, const short* __restrict__ Wt,
    short* __restrict__ Qrm, short* __restrict__ Krm, short* __restrict__ VT) {
    const int raw = blockIdx.x;              // [0,768)
    const int xcd = raw & 7;
    const int rest = raw >> 3;               // [0,96)
    const int cblk = rest & 7;
    const int t = rest >> 3;                 // [0,12)
    const int z = t >> 2;
    const int m0 = (xcd * 4 + (t & 3)) * 128;
    const int c0 = cblk * 128;

    const short* Bt = Wt + (size_t)z * cM * cIn;
    __shared__ short smem[128 * 132];   // gemm_core uses first 16384 shorts
    const int tid = threadIdx.x, w = tid >> 6, l = tid & 63;
    const int m16 = l & 15, g = l >> 4;
    const int mq = (w & 1) * 64, nq = (w >> 1) * 64;
    f32x4 acc[4][4] = {};

    if (z <= 1) {
        gemm_core<false>(hbf, Bt, smem, m0, c0, tid, acc);
        __syncthreads();
        #pragma unroll
        for (int i = 0; i < 4; i++)
            #pragma unroll
            for (int j = 0; j < 4; j++)
                #pragma unroll
                for (int r = 0; r < 4; r++)
                    smem[(mq + i * 16 + g * 4 + r) * 132 + nq + j * 16 + m16] =
                        f2bf(acc[i][j][r]);
        __syncthreads();
        const int tr = tid >> 1, hf = (tid & 1) * 64;
        short* dst = ((z == 0) ? Qrm : Krm) + (size_t)(m0 + tr) * cM + c0 + hf;
        #pragma unroll
        for (int c = 0; c < 8; c++)
            *(bf16x8*)(dst + c * 8) = *(const bf16x8*)(smem + tr * 132 + hf + c * 8);
    } else {
        gemm_core<true>(hbf, Bt, smem, m0, c0, tid, acc);
        __syncthreads();
        #pragma unroll
        for (int i = 0; i < 4; i++) {
            const int sl = mq + i * 16 + m16;
            const int s6 = sl & 63;
            const int pcol = (sl & 64) +
                             ((s6 & 3) | ((s6 & 28) << 1) | ((s6 >> 3) & 4));
            #pragma unroll
            for (int j = 0; j < 4; j++)
                #pragma unroll
                for (int r = 0; r < 4; r++)
                    smem[(nq + j * 16 + g * 4 + r) * 132 + pcol] =
                        f2bf(acc[i][j][r]);
        }
        __syncthreads();
        const int tr = tid >> 1, hf = (tid & 1) * 64;
        const int wcol = c0 + tr;           // h*64 + d
        short* dst = VT + (((size_t)(m0 >> 11) * cH + (wcol >> 6)) * cD +
                           (wcol & 63)) * cS + (m0 & 2047) + hf;
        #pragma unroll
        for (int c = 0; c < 8; c++)
            *(bf16x8*)(dst + c * 8) = *(const bf16x8*)(smem + tr * 132 + hf + c * 8);
    }
}

// ---------------------------------------------------------------------------
// Kernel 4: flash attention (8-wave blocks, qq=2, KVBLK=128, XCD-pinned,
// K+V dbuf LDS, LDS bias window, bias+mask folded into MFMA acc-init,
// mask row in LDS) — R11-proven, unchanged.
// ---------------------------------------------------------------------------
__global__ __launch_bounds__(512, 1) void attn_kernel(
    const short* __restrict__ Qrm, const short* __restrict__ Krm,
    const short* __restrict__ VTK, const float* __restrict__ maskadd,
    const float* __restrict__ bias_t, short* __restrict__ ctx) {
    // raw -> (xcd, q-block, bh-group): all 8 q-blocks of a (b,h) on one XCD
    const int raw = blockIdx.x;              // [0,256)
    const int xcd = raw & 7, j = raw >> 3;
    const int qi = j & 7, grp = j >> 3;      // grp in [0,4)
    const int bh = grp * 8 + xcd;            // [0,32)
    const int b = bh >> 4, h = bh & 15;
    const int q0 = qi * 256;

    const short* VTp = VTK + ((size_t)b * cH + h) * cS * cD;   // [d][kappa]
    const float* mp = maskadd + b * cS;

    const int tid = threadIdx.x;             // [0,512)
    const int wave = tid >> 6, lane = tid & 63;
    const int m16 = lane & 15, g = lane >> 4;

    __shared__ short Kt[2][128 * 64];    // [buf][key][d-unit swz]   32 KB
    __shared__ short Vt[2][64 * 128];    // [buf][d][kappa-unit swz] 32 KB
    __shared__ float bias_lds[2304];     // delta window, 9.2 KB
    __shared__ float mask_lds[2048];     // this batch's mask row, 8 KB

    // ---- stage bias window + mask row once
    {
        const float* bw = bias_t + h * 4096 + 2048 - (q0 + 255);
        for (int i = tid; i < 2303; i += 512)
            bias_lds[i] = bw[i];
        ((f32x4*)mask_lds)[tid & 511] = ((const f32x4*)mp)[tid & 511];
    }

    int qv[2];
    bf16x8 qf[2][2];
    #pragma unroll
    for (int qq = 0; qq < 2; qq++) {
        qv[qq] = q0 + wave * 16 + qq * 128 + m16;
        const short* qb = Qrm + (size_t)(b * cS + qv[qq]) * cM + h * cD;
        qf[qq][0] = *(const bf16x8*)(qb + g * 8);
        qf[qq][1] = *(const bf16x8*)(qb + 32 + g * 8);
    }

    // per-lane base index into bias_lds: idx = ib[qq] + kt + st*16 + c
    int ib[2];
    #pragma unroll
    for (int qq = 0; qq < 2; qq++)
        ib[qq] = q0 + 255 + g * 4 - qv[qq];

    f32x4 o[2][4] = {};
    f32x4 lacc[2] = {};
    BfPack ones;
    #pragma unroll
    for (int i = 0; i < 8; i++) ones.s[i] = (short)0x3F80;   // bf16 1.0

    // staging: 512 threads -> 2 async16 per array per tile
    const int u8 = tid & 7, r8 = tid >> 3;      // r8 in [0,64)
    const int u16s = tid & 15, r16 = tid >> 4;  // r16 in [0,32)
    const short* pK = Krm + ((size_t)b * cS + r8) * cM + h * cD +
                      ((u8 ^ (r8 & 7)) << 3);
    const short* pV = VTp + (size_t)r16 * cS + ((u16s ^ (r16 & 7)) << 3);
    short* dK = (short*)Kt + tid * 8;
    short* dV = (short*)Vt + tid * 8;

    const int kx0 = ((g ^ (m16 & 7)) << 3);          // lo 16B unit
    const int kx1 = (((g + 4) ^ (m16 & 7)) << 3);    // hi 16B unit

    #pragma unroll
    for (int c = 0; c < 2; c++) {
        async16(pK + (size_t)(c * 64) * cM, dK + c * 4096);
        async16(pV + (size_t)(c * 32) * cS, dV + c * 4096);
    }
    __syncthreads();        // bias/mask staged + tile 0 landed

    for (int kt = 0; kt < cS; kt += 128) {
        const int buf = (kt >> 7) & 1, nxt = buf ^ 1;
        if (kt + 128 < cS) {           // stage next tile (uniform branch)
            #pragma unroll
            for (int c = 0; c < 2; c++) {
                async16(pK + (size_t)(kt + 128 + c * 64) * cM,
                        dK + nxt * 8192 + c * 4096);
                async16(pV + (size_t)(c * 32) * cS + kt + 128,
                        dV + nxt * 8192 + c * 4096);
            }
        }
        const short* K_ = (const short*)Kt + buf * 8192;
        const short* V_ = (const short*)Vt + buf * 8192;
        const int iq0 = ib[0] + kt, iq1 = ib[1] + kt;   // 2 adds per tile

        #pragma unroll
        for (int h2 = 0; h2 < 2; h2++) {
            // ---- bias + mask from LDS (compile-time DS offsets)
            f32x4 binit[2][4];
            #pragma unroll
            for (int t4 = 0; t4 < 4; t4++) {
                const int sto = (h2 * 4 + t4) * 16;
                f32x4 mk = *(const f32x4*)(mask_lds + kt + sto + g * 4);
                #pragma unroll
                for (int c = 0; c < 4; c++) {
                    binit[0][t4][c] = bias_lds[iq0 + sto + c] + mk[c];
                    binit[1][t4][c] = bias_lds[iq1 + sto + c] + mk[c];
                }
            }

            // ---- S^T with bias+mask pre-loaded into the accumulator
            f32x4 s[2][4];
            __builtin_amdgcn_s_setprio(1);
            #pragma unroll
            for (int t4 = 0; t4 < 4; t4++) {
                const int st = h2 * 4 + t4;
                bf16x8 klo = *(const bf16x8*)(K_ + (st * 16 + m16) * 64 + kx0);
                bf16x8 khi = *(const bf16x8*)(K_ + (st * 16 + m16) * 64 + kx1);
                #pragma unroll
                for (int qq = 0; qq < 2; qq++)
                    s[qq][t4] = mfma16(khi, qf[qq][1],
                                       mfma16(klo, qf[qq][0], binit[qq][t4]));
            }
            __builtin_amdgcn_s_setprio(0);

            // ---- softmax numerator: exp2(s), pack P frags
            BfPack pp[2][2];
            #pragma unroll
            for (int qq = 0; qq < 2; qq++)
                #pragma unroll
                for (int t4 = 0; t4 < 4; t4++)
                    #pragma unroll
                    for (int r = 0; r < 2; r++) {
                        float p0 = __builtin_amdgcn_exp2f(s[qq][t4][2 * r]);
                        float p1 = __builtin_amdgcn_exp2f(s[qq][t4][2 * r + 1]);
                        __hip_bfloat162 h2v = __float22bfloat162_rn(float2{p0, p1});
                        short2 sp = *(short2*)&h2v;
                        pp[qq][t4 & 1].s[(t4 >> 1) * 4 + 2 * r]     = sp.x;
                        pp[qq][t4 & 1].s[(t4 >> 1) * 4 + 2 * r + 1] = sp.y;
                    }

            // ---- denominator on the matrix pipe + O^T = V^T @ P
            __builtin_amdgcn_s_setprio(1);
            #pragma unroll
            for (int qq = 0; qq < 2; qq++) {
                lacc[qq] = mfma16(ones.v, pp[qq][0].v, lacc[qq]);
                lacc[qq] = mfma16(ones.v, pp[qq][1].v, lacc[qq]);
            }
            #pragma unroll
            for (int nt = 0; nt < 4; nt++) {
                bf16x8 vlo = *(const bf16x8*)(V_ + (nt * 16 + m16) * 128 +
                                              h2 * 64 + kx0);
                bf16x8 vhi = *(const bf16x8*)(V_ + (nt * 16 + m16) * 128 +
                                              h2 * 64 + kx1);
                #pragma unroll
                for (int qq = 0; qq < 2; qq++) {
                    o[qq][nt] = mfma16(vlo, pp[qq][0].v, o[qq][nt]);
                    o[qq][nt] = mfma16(vhi, pp[qq][1].v, o[qq][nt]);
                }
            }
            __builtin_amdgcn_s_setprio(0);
        }

        __syncthreads();   // staging (nxt) complete + all reads of buf done
    }

    #pragma unroll
    for (int qq = 0; qq < 2; qq++) {
        const float inv = 1.0f / lacc[qq][0];   // all 4 regs identical
        short* cb = ctx + (size_t)(b * cS + qv[qq]) * cM + h * cD;
        #pragma unroll
        for (int nt = 0; nt < 4; nt++) {
            BfPack4 pk;
            #pragma unroll
            for (int r = 0; r < 4; r++) pk.s[r] = f2bf(o[qq][nt][r] * inv);
            *(s16x4*)(cb + nt * 16 + g * 4) = pk.v;
        }
    }
}

// ---------------------------------------------------------------------------
// Kernel 5: out fp32 = ctx(bf16) @ WoT.  64x128 tile, 512 blocks,
// XCD-pinned 1-D grid, 2-phase double-buffered staging (R10-proven).
// ---------------------------------------------------------------------------
__global__ __launch_bounds__(256) void gemm_o_kernel(
    const short* __restrict__ ctx, const short* __restrict__ WoT,
    float* __restrict__ out) {
    const int raw = blockIdx.x;              // [0,512)
    const int xcd = raw & 7;
    const int rest = raw >> 3;               // [0,64)
    const int cblk = rest & 7;
    const int m0 = (xcd * 8 + (rest >> 3)) * 64;
    const int c0 = cblk * 128;

    __shared__ short smem[12288];        // 2 bufs x (sA 2048 + sB 4096)
    const int tid = threadIdx.x, w = tid >> 6, l = tid & 63;
    const int m16 = l & 15, g = l >> 4;
    const int wm = (w & 1) * 32, wn = (w >> 1) * 64;
    const int sr = tid >> 2, sc = (tid & 3) * 8;
    f32x4 acc[2][4] = {};

    const short* pA = ctx + (size_t)(m0 + sr) * cIn + sc;
    const short* pB0 = WoT + (size_t)(c0 + sr) * cIn + sc;
    const short* pB1 = WoT + (size_t)(c0 + 64 + sr) * cIn + sc;

    // prologue: k0 = 0 -> buf 0
    async16(pA, smem + tid * 8);
    async16(pB0, smem + 2048 + tid * 8);
    async16(pB1, smem + 4096 + tid * 8);
    __syncthreads();

    for (int k0 = 0; k0 < cIn; k0 += 32) {
        const int buf = (k0 >> 5) & 1;
        if (k0 + 32 < cIn) {           // stage next K-step
            short* dn = smem + (buf ^ 1) * 6144 + tid * 8;
            async16(pA + k0 + 32, dn);
            async16(pB0 + k0 + 32, dn + 2048);
            async16(pB1 + k0 + 32, dn + 4096);
        }
        const short* sA = smem + buf * 6144;
        const short* sB = sA + 2048;
        bf16x8 af[2], bf[4];
        #pragma unroll
        for (int i = 0; i < 2; i++)
            af[i] = *(const bf16x8*)(sA + (wm + i * 16 + m16) * 32 + g * 8);
        #pragma unroll
        for (int jj = 0; jj < 4; jj++)
            bf[jj] = *(const bf16x8*)(sB + (wn + jj * 16 + m16) * 32 + g * 8);
        #pragma unroll
        for (int i = 0; i < 2; i++)
            #pragma unroll
            for (int jj = 0; jj < 4; jj++)
                acc[i][jj] = mfma16(af[i], bf[jj], acc[i][jj]);
        __syncthreads();   // staging (buf^1) landed + all reads of buf done
    }
    #pragma unroll
    for (int i = 0; i < 2; i++)
        #pragma unroll
        for (int jj = 0; jj < 4; jj++)
            #pragma unroll
            for (int r = 0; r < 4; r++)
                out[(size_t)(m0 + wm + i * 16 + g * 4 + r) * cM +
                    c0 + wn + jj * 16 + m16] = acc[i][jj][r];
}

extern "C" void kernel_launch(void* const* d_in, const int* in_sizes, int n_in,
                              void* d_out, int out_size, void* d_ws, size_t ws_size,
                              hipStream_t stream) {
    const float* hidden   = (const float*)d_in[0];
    const int*   mask     = (const int*)d_in[1];
    const float* Wq       = (const float*)d_in[2];
    const float* Wk       = (const float*)d_in[3];
    const float* Wv       = (const float*)d_in[4];
    const float* Wo       = (const float*)d_in[5];
    const float* rel_bias = (const float*)d_in[6];
    float* out = (float*)d_out;

    // ws (shorts): hbf/ctx 4M | Wt 4x1M | Q 4M | K 4M | VT 4M | bias 256KB | mask 16KB
    short* hbf_ctx = (short*)d_ws;
    short* Wt  = hbf_ctx + (size_t)4 * 1024 * 1024;
    short* Qrm = Wt  + (size_t)4 * 1024 * 1024;
    short* Krm = Qrm + (size_t)4 * 1024 * 1024;
    short* VT  = Krm + (size_t)4 * 1024 * 1024;
    float* bias_t  = (float*)(VT + (size_t)4 * 1024 * 1024);
    float* maskf   = bias_t + 16 * 4096;

    prep_kernel<<<3088, 256, 0, stream>>>(hidden, hbf_ctx, Wq, Wk, Wv, Wo, Wt,
                                          rel_bias, mask, bias_t, maskf);
    gemm_qkv_kernel<<<768, 256, 0, stream>>>(hbf_ctx, Wt, Qrm, Krm, VT);
    attn_kernel<<<256, 512, 0, stream>>>(Qrm, Krm, VT, maskf, bias_t, hbf_ctx);
    gemm_o_kernel<<<512, 256, 0, stream>>>(hbf_ctx, Wt + (size_t)3 * 1024 * 1024,
                                           out);
}